// Round 7
// baseline (483.040 us; speedup 1.0000x reference)
//
#include <hip/hip_runtime.h>

#define HH 512
#define WW 512
#define NB 4

// ---------------- Stage 1: 11x11 convs (1->8, pos & neg) + spike/WTA logic ----------------
// Round-11 version (2 px/thread, 2048 blocks). Stage1 proven insensitive to DS/s_load/TLP.
#define K1 11
#define PAD1 5
#define T1X 32
#define T1Y 16
#define IN1X 42
#define IN1Y 26
#define S1 44

__device__ __forceinline__ unsigned conv8_pass2(const float* __restrict__ sm,
                                                const float* __restrict__ Wb,
                                                int py, int px)
{
    float acc[8][2];
    #pragma unroll
    for (int c = 0; c < 8; c++) { acc[c][0] = 0.f; acc[c][1] = 0.f; }

    #pragma unroll 1
    for (int ky = 0; ky < K1; ky++) {
        const float2* rp = (const float2*)&sm[(py + ky) * S1 + px];
        float a[12];
        #pragma unroll
        for (int r = 0; r < 6; r++) *(float2*)&a[2 * r] = rp[r];
        #pragma unroll
        for (int c = 0; c < 8; c++) {
            #pragma unroll
            for (int kx = 0; kx < K1; kx++) {
                const float wv = Wb[c * 121 + ky * 11 + kx];
                acc[c][0] = fmaf(a[kx],     wv, acc[c][0]);
                acc[c][1] = fmaf(a[kx + 1], wv, acc[c][1]);
            }
        }
    }
    unsigned bits = 0;
    #pragma unroll
    for (int c = 0; c < 8; c++) {
        bits |= (acc[c][0] >= 1.f ? 1u : 0u) << (c * 2);
        bits |= (acc[c][1] >= 1.f ? 1u : 0u) << (c * 2 + 1);
    }
    return bits;
}

__global__ __launch_bounds__(256, 8) void stage1_kernel(
    const float* __restrict__ inp, const float* __restrict__ Wb,
    unsigned char* __restrict__ border)
{
    __shared__ __align__(16) float s0[IN1Y * S1];
    __shared__ __align__(16) float s1[IN1Y * S1];

    const int b   = blockIdx.z;
    const int tx0 = blockIdx.x * T1X;
    const int ty0 = blockIdx.y * T1Y;
    const float* in0 = inp + ((size_t)b * 2 + 0) * (HH * WW);
    const float* in1 = inp + ((size_t)b * 2 + 1) * (HH * WW);

    for (int i = threadIdx.x; i < IN1Y * IN1X; i += 256) {
        int iy = i / IN1X, ix = i - iy * IN1X;
        int gy = ty0 + iy - PAD1, gx = tx0 + ix - PAD1;
        bool ok = (gy >= 0) & (gy < HH) & (gx >= 0) & (gx < WW);
        int idx = gy * WW + gx;
        s0[iy * S1 + ix] = ok ? in0[idx] : 0.f;
        s1[iy * S1 + ix] = ok ? in1[idx] : 0.f;
    }
    __syncthreads();

    const int lx = threadIdx.x & 15;
    const int ly = threadIdx.x >> 4;
    const int px = lx * 2;
    const int py = ly;

    const unsigned bitP = conv8_pass2(s0, Wb, py, px);
    const unsigned bitN = conv8_pass2(s1, Wb, py, px);

    const int gy = ty0 + py;
    const int gxbase = tx0 + px;

    float vm[2];
    #pragma unroll
    for (int p = 0; p < 2; p++)
        vm[p] = s0[(py + PAD1) * S1 + px + PAD1 + p]
              + s1[(py + PAD1) * S1 + px + PAD1 + p];

    float b13[4][2], b24[4][2];
    #pragma unroll
    for (int o = 0; o < 4; o++) {
        #pragma unroll
        for (int p = 0; p < 2; p++) {
            float pe = (float)((bitP >> (4 * o + p))     & 1u);
            float po = (float)((bitP >> (4 * o + 2 + p)) & 1u);
            float ne = (float)((bitN >> (4 * o + p))     & 1u);
            float no = (float)((bitN >> (4 * o + 2 + p)) & 1u);
            float sa = (vm[p] * (pe - 1.5f * no) >= 1.f) ? 1.f : 0.f;
            float sb = (vm[p] * (ne - 1.5f * po) >= 1.f) ? 1.f : 0.f;
            b13[o][p] = sa + sb;
            float sc = (vm[p] * (po - 1.5f * ne) >= 1.f) ? 1.f : 0.f;
            float sd = (vm[p] * (no - 1.5f * pe) >= 1.f) ? 1.f : 0.f;
            b24[o][p] = sc + sd;
        }
    }
    float mxp[2];
    #pragma unroll
    for (int p = 0; p < 2; p++) {
        float m = 0.f;
        #pragma unroll
        for (int o = 0; o < 4; o++) m = fmaxf(m, fabsf(b13[o][p] - b24[o][p]));
        mxp[p] = m;
    }
    #pragma unroll
    for (int o = 0; o < 4; o++) {
        unsigned short w0 = 0, w1 = 0, w2 = 0, w3 = 0;
        #pragma unroll
        for (int p = 0; p < 2; p++) {
            float d   = b13[o][p] - b24[o][p];
            float wta = (fabsf(d) == mxp[p]) ? 1.f : 0.f;
            float b1p = (wta * d >= 1.f)    ? 1.f : 0.f;
            float b1n = (-(wta * d) >= 1.f) ? 1.f : 0.f;
            w0 |= (unsigned short)(unsigned char)(b1p * b13[o][p]) << (8 * p);
            w1 |= (unsigned short)(unsigned char)(b1p * b24[o][p]) << (8 * p);
            w2 |= (unsigned short)(unsigned char)(b1n * b24[o][p]) << (8 * p);
            w3 |= (unsigned short)(unsigned char)(b1n * b13[o][p]) << (8 * p);
        }
        size_t base = (((size_t)b * 16 + 4 * o) * HH + gy) * WW + gxbase;
        *(unsigned short*)&border[base]                       = w0;
        *(unsigned short*)&border[base + (size_t)HH * WW]     = w1;
        *(unsigned short*)&border[base + (size_t)2 * HH * WW] = w2;
        *(unsigned short*)&border[base + (size_t)3 * HH * WW] = w3;
    }
}

// ---------------- Stage 2: depthwise 23x23 conv, u8 LDS tile ----------------
// Round-17: EXACT round-15 structure (165.6 us) with ONE change: interior
// t-loop `#pragma unroll 2`. r15's `unroll 1` forbade cross-iteration code
// motion, so each t paid exposed ds_read (~120cy) + s_load (~300cy) latency
// at the loop top (the TLP-independent ~21% idle). With a 2-iteration
// straight-line body the scheduler can hoist t+1's loads above t's 1472-FMA
// wall. r16 (per-lane vmcnt weights) is refuted and reverted.
#define K2 23
#define PAD2 11
#define T2X 32
#define T2Y 512
#define SROW 18        // LDS row stride in dwords (72 B); even -> b64-aligned reads
#define R2 534         // staged rows: -11 .. 522

__device__ __forceinline__ float ubyte_f(unsigned dw, int byi) {
    return (float)((dw >> (8 * byi)) & 0xffu);   // -> v_cvt_f32_ubyteN
}

// load + convert one staged row (30 px window for 8-px group at lx)
__device__ __forceinline__ void s2_row(const unsigned* __restrict__ tile,
                                       int trow, int lx, float a[31])
{
    unsigned d[8];
    const uint2* tp2 = (const uint2*)&tile[trow * SROW + 2 * lx];
    #pragma unroll
    for (int r2 = 0; r2 < 4; r2++) {
        uint2 v = tp2[r2];
        d[2 * r2] = v.x; d[2 * r2 + 1] = v.y;
    }
    #pragma unroll
    for (int j = 1; j <= 30; j++) a[j] = ubyte_f(d[j >> 2], j & 3);
}

__global__ __launch_bounds__(256, 4) void stage2_kernel(
    const unsigned char* __restrict__ border, const float* __restrict__ Wg,
    unsigned char* __restrict__ gsp)
{
    __shared__ unsigned tile[R2 * SROW];   // u8 tile, 38.4 KB

    const int z   = blockIdx.z;
    const int b   = z >> 4;
    const int c   = z & 15;
    const int tx0 = blockIdx.x * T2X;
    const unsigned char* bp = border + ((size_t)b * 16 + c) * (HH * WW);

    // ---- stage u8 rows [-11, 523), cols [tx0-12, tx0+52) as dwords ----
    for (int i = threadIdx.x; i < R2 * 16; i += 256) {
        int iy = i >> 4, cc = i & 15;
        int gy  = iy - PAD2;
        int gx0 = tx0 - 12 + 4 * cc;       // 4-aligned; in range iff 0<=gx0<=508
        unsigned u = 0;
        if (((unsigned)gy < HH) & ((unsigned)gx0 < WW))
            u = *(const unsigned*)(bp + (size_t)gy * WW + gx0);
        tile[iy * SROW + cc] = u;
    }
    __syncthreads();

    const int lx = threadIdx.x & 3;    // 4 x-groups of 8 px -> 32 wide
    const int ly = threadIdx.x >> 2;   // 64 y-groups of 8 rows -> 512 tall
    const int px = lx * 8;
    const int py = ly * 8;

    float acc[8][8];
    #pragma unroll
    for (int dy = 0; dy < 8; dy++)
        #pragma unroll
        for (int p = 0; p < 8; p++) acc[dy][p] = 0.f;

    const float* wc = Wg + c * (K2 * K2);

    // ---- boundary rows t=0..6: dy FULLY unrolled, static acc, uniform guard ----
    #pragma unroll 1
    for (int t = 0; t < 7; t++) {
        float a[31];
        s2_row(tile, py + t, lx, a);
        #pragma unroll
        for (int dy = 0; dy < 8; dy++) {
            if (t - dy >= 0) {                 // runtime-uniform; acc idx static
                const float* wr = wc + (t - dy) * K2;
                #pragma unroll
                for (int kx = 0; kx < K2; kx++) {
                    const float wv = wr[kx];
                    #pragma unroll
                    for (int p = 0; p < 8; p++)
                        acc[dy][p] = fmaf(a[p + kx + 1], wv, acc[dy][p]);
                }
            }
        }
    }

    // ---- interior rows t=7..22: all 8 dy active, dy innermost, branch-free.
    //      unroll 2: lets the scheduler hoist t+1's ds_read/s_load above
    //      t's FMA block (the r15 stall). ----
    #pragma unroll 2
    for (int t = 7; t < 23; t++) {
        float a[31];
        s2_row(tile, py + t, lx, a);
        const float* w0 = wc + t * K2;       // dy=d row is w0[kx - 23*d]
        #pragma unroll
        for (int kx = 0; kx < K2; kx++) {
            float wv[8];
            #pragma unroll
            for (int d = 0; d < 8; d++) wv[d] = w0[kx - 23 * d];
            #pragma unroll
            for (int p = 0; p < 8; p++) {
                const float av = a[p + kx + 1];
                #pragma unroll
                for (int d = 0; d < 8; d++)
                    acc[d][p] = fmaf(av, wv[d], acc[d][p]);
            }
        }
    }

    // ---- boundary rows t=23..29: dy FULLY unrolled, static acc, uniform guard ----
    #pragma unroll 1
    for (int t = 23; t < 30; t++) {
        float a[31];
        s2_row(tile, py + t, lx, a);
        #pragma unroll
        for (int dy = 0; dy < 8; dy++) {
            if (t - dy < K2) {                 // runtime-uniform; acc idx static
                const float* wr = wc + (t - dy) * K2;
                #pragma unroll
                for (int kx = 0; kx < K2; kx++) {
                    const float wv = wr[kx];
                    #pragma unroll
                    for (int p = 0; p < 8; p++)
                        acc[dy][p] = fmaf(a[p + kx + 1], wv, acc[dy][p]);
                }
            }
        }
    }

    // ---- spike + write u8 plane ----
    const int ox = tx0 + px;               // multiple of 8 -> uint2 store OK
    unsigned char* gp = gsp + ((size_t)b * 16 + c) * (HH * WW);
    #pragma unroll
    for (int dy = 0; dy < 8; dy++) {
        const int oy = py + dy;
        unsigned lo = 0, hi = 0;
        #pragma unroll
        for (int p = 0; p < 4; p++) lo |= (acc[dy][p]     >= 1.f ? 1u : 0u) << (8 * p);
        #pragma unroll
        for (int p = 0; p < 4; p++) hi |= (acc[dy][p + 4] >= 1.f ? 1u : 0u) << (8 * p);
        uint2 v; v.x = lo; v.y = hi;
        *(uint2*)&gp[(size_t)oy * WW + ox] = v;
    }
}

// ---------------- Stage 3: combine 16 spike planes -> output ----------------
__global__ __launch_bounds__(256) void combine_kernel(
    const unsigned char* __restrict__ gsp, float* __restrict__ out)
{
    const int idx = blockIdx.x * 256 + threadIdx.x;   // uint granules
    const int b = idx >> 16;
    const int r = idx & 65535;
    const unsigned* g = (const unsigned*)gsp;
    const int pb = b * 16;
    unsigned s = 0;
    #pragma unroll
    for (int o = 0; o < 4; o++) {
        unsigned g0 = g[(size_t)(pb + 4 * o + 0) * 65536 + r];
        unsigned g1 = g[(size_t)(pb + 4 * o + 1) * 65536 + r];
        unsigned g2 = g[(size_t)(pb + 4 * o + 2) * 65536 + r];
        unsigned g3 = g[(size_t)(pb + 4 * o + 3) * 65536 + r];
        s += ((g0 & ~g1) & 0x01010101u) + ((g2 & ~g3) & 0x01010101u);
    }
    float4 f;
    f.x = (float)(s & 255u);
    f.y = (float)((s >> 8) & 255u);
    f.z = (float)((s >> 16) & 255u);
    f.w = (float)(s >> 24);
    ((float4*)out)[idx] = f;
}

extern "C" void kernel_launch(void* const* d_in, const int* in_sizes, int n_in,
                              void* d_out, int out_size, void* d_ws, size_t ws_size,
                              hipStream_t stream)
{
    const float* inp = (const float*)d_in[0];   // (4,2,512,512) f32
    const float* Wb  = (const float*)d_in[1];   // (8,1,11,11)   f32
    const float* Wg  = (const float*)d_in[2];   // (16,1,23,23)  f32
    unsigned char* border = (unsigned char*)d_ws;                       // 16.78 MB
    unsigned char* gsp    = border + (size_t)NB * 16 * HH * WW;         // +16.78 MB
    float* out = (float*)d_out;                 // (4,512,512)   f32

    dim3 blk(256);
    dim3 g1(WW / T1X, HH / T1Y, NB);        // 16x32x4 = 2048 blocks
    stage1_kernel<<<g1, blk, 0, stream>>>(inp, Wb, border);
    dim3 g2(WW / T2X, 1, NB * 16);          // 16x1x64 = 1024 blocks, 4/CU resident
    stage2_kernel<<<g2, blk, 0, stream>>>(border, Wg, gsp);
    dim3 g3((NB * HH * WW / 4) / 256);      // 1024 blocks
    combine_kernel<<<g3, blk, 0, stream>>>(gsp, out);
}

// Round 8
// 271.986 us; speedup vs baseline: 1.7760x; 1.7760x over previous
//
#include <hip/hip_runtime.h>

#define HH 512
#define WW 512
#define NB 4

// ---------------- Stage 1: 11x11 convs (1->8, pos & neg) + spike/WTA logic ----------------
// Round-11 version (2 px/thread, 2048 blocks). Stage1 proven insensitive to DS/s_load/TLP.
#define K1 11
#define PAD1 5
#define T1X 32
#define T1Y 16
#define IN1X 42
#define IN1Y 26
#define S1 44

__device__ __forceinline__ unsigned conv8_pass2(const float* __restrict__ sm,
                                                const float* __restrict__ Wb,
                                                int py, int px)
{
    float acc[8][2];
    #pragma unroll
    for (int c = 0; c < 8; c++) { acc[c][0] = 0.f; acc[c][1] = 0.f; }

    #pragma unroll 1
    for (int ky = 0; ky < K1; ky++) {
        const float2* rp = (const float2*)&sm[(py + ky) * S1 + px];
        float a[12];
        #pragma unroll
        for (int r = 0; r < 6; r++) *(float2*)&a[2 * r] = rp[r];
        #pragma unroll
        for (int c = 0; c < 8; c++) {
            #pragma unroll
            for (int kx = 0; kx < K1; kx++) {
                const float wv = Wb[c * 121 + ky * 11 + kx];
                acc[c][0] = fmaf(a[kx],     wv, acc[c][0]);
                acc[c][1] = fmaf(a[kx + 1], wv, acc[c][1]);
            }
        }
    }
    unsigned bits = 0;
    #pragma unroll
    for (int c = 0; c < 8; c++) {
        bits |= (acc[c][0] >= 1.f ? 1u : 0u) << (c * 2);
        bits |= (acc[c][1] >= 1.f ? 1u : 0u) << (c * 2 + 1);
    }
    return bits;
}

__global__ __launch_bounds__(256, 8) void stage1_kernel(
    const float* __restrict__ inp, const float* __restrict__ Wb,
    unsigned char* __restrict__ border)
{
    __shared__ __align__(16) float s0[IN1Y * S1];
    __shared__ __align__(16) float s1[IN1Y * S1];

    const int b   = blockIdx.z;
    const int tx0 = blockIdx.x * T1X;
    const int ty0 = blockIdx.y * T1Y;
    const float* in0 = inp + ((size_t)b * 2 + 0) * (HH * WW);
    const float* in1 = inp + ((size_t)b * 2 + 1) * (HH * WW);

    for (int i = threadIdx.x; i < IN1Y * IN1X; i += 256) {
        int iy = i / IN1X, ix = i - iy * IN1X;
        int gy = ty0 + iy - PAD1, gx = tx0 + ix - PAD1;
        bool ok = (gy >= 0) & (gy < HH) & (gx >= 0) & (gx < WW);
        int idx = gy * WW + gx;
        s0[iy * S1 + ix] = ok ? in0[idx] : 0.f;
        s1[iy * S1 + ix] = ok ? in1[idx] : 0.f;
    }
    __syncthreads();

    const int lx = threadIdx.x & 15;
    const int ly = threadIdx.x >> 4;
    const int px = lx * 2;
    const int py = ly;

    const unsigned bitP = conv8_pass2(s0, Wb, py, px);
    const unsigned bitN = conv8_pass2(s1, Wb, py, px);

    const int gy = ty0 + py;
    const int gxbase = tx0 + px;

    float vm[2];
    #pragma unroll
    for (int p = 0; p < 2; p++)
        vm[p] = s0[(py + PAD1) * S1 + px + PAD1 + p]
              + s1[(py + PAD1) * S1 + px + PAD1 + p];

    float b13[4][2], b24[4][2];
    #pragma unroll
    for (int o = 0; o < 4; o++) {
        #pragma unroll
        for (int p = 0; p < 2; p++) {
            float pe = (float)((bitP >> (4 * o + p))     & 1u);
            float po = (float)((bitP >> (4 * o + 2 + p)) & 1u);
            float ne = (float)((bitN >> (4 * o + p))     & 1u);
            float no = (float)((bitN >> (4 * o + 2 + p)) & 1u);
            float sa = (vm[p] * (pe - 1.5f * no) >= 1.f) ? 1.f : 0.f;
            float sb = (vm[p] * (ne - 1.5f * po) >= 1.f) ? 1.f : 0.f;
            b13[o][p] = sa + sb;
            float sc = (vm[p] * (po - 1.5f * ne) >= 1.f) ? 1.f : 0.f;
            float sd = (vm[p] * (no - 1.5f * pe) >= 1.f) ? 1.f : 0.f;
            b24[o][p] = sc + sd;
        }
    }
    float mxp[2];
    #pragma unroll
    for (int p = 0; p < 2; p++) {
        float m = 0.f;
        #pragma unroll
        for (int o = 0; o < 4; o++) m = fmaxf(m, fabsf(b13[o][p] - b24[o][p]));
        mxp[p] = m;
    }
    #pragma unroll
    for (int o = 0; o < 4; o++) {
        unsigned short w0 = 0, w1 = 0, w2 = 0, w3 = 0;
        #pragma unroll
        for (int p = 0; p < 2; p++) {
            float d   = b13[o][p] - b24[o][p];
            float wta = (fabsf(d) == mxp[p]) ? 1.f : 0.f;
            float b1p = (wta * d >= 1.f)    ? 1.f : 0.f;
            float b1n = (-(wta * d) >= 1.f) ? 1.f : 0.f;
            w0 |= (unsigned short)(unsigned char)(b1p * b13[o][p]) << (8 * p);
            w1 |= (unsigned short)(unsigned char)(b1p * b24[o][p]) << (8 * p);
            w2 |= (unsigned short)(unsigned char)(b1n * b24[o][p]) << (8 * p);
            w3 |= (unsigned short)(unsigned char)(b1n * b13[o][p]) << (8 * p);
        }
        size_t base = (((size_t)b * 16 + 4 * o) * HH + gy) * WW + gxbase;
        *(unsigned short*)&border[base]                       = w0;
        *(unsigned short*)&border[base + (size_t)HH * WW]     = w1;
        *(unsigned short*)&border[base + (size_t)2 * HH * WW] = w2;
        *(unsigned short*)&border[base + (size_t)3 * HH * WW] = w3;
    }
}

// ---------------- Stage 2: depthwise 23x23 conv, u8 LDS tile ----------------
// Round-18: r15 structure (165.6 us, proven) + rolling dc[8] register
// prefetch: each iteration converts the PREVIOUS ds_read result (no wait),
// then issues next row's 4x ds_read_b64 whose lgkm wait lands after the
// FMA wall. +8 VGPR only (r17's unroll-2 spilled acc via 2x a[31]; r16's
// vmcnt weights refuted — weights stay on s_load).
#define K2 23
#define PAD2 11
#define T2X 32
#define T2Y 512
#define SROW 18        // LDS row stride in dwords (72 B); even -> b64-aligned reads
#define R2 534         // staged rows: -11 .. 522

__device__ __forceinline__ float ubyte_f(unsigned dw, int byi) {
    return (float)((dw >> (8 * byi)) & 0xffu);   // -> v_cvt_f32_ubyteN
}

// issue one staged row's 4x ds_read_b64 (8 dwords, 30 px window at lx)
__device__ __forceinline__ void s2_load(const unsigned* __restrict__ tile,
                                        int trow, int lx, unsigned d[8])
{
    const uint2* tp2 = (const uint2*)&tile[trow * SROW + 2 * lx];
    #pragma unroll
    for (int r2 = 0; r2 < 4; r2++) {
        uint2 v = tp2[r2];
        d[2 * r2] = v.x; d[2 * r2 + 1] = v.y;
    }
}

__device__ __forceinline__ void s2_cvt(const unsigned d[8], float a[31])
{
    #pragma unroll
    for (int j = 1; j <= 30; j++) a[j] = ubyte_f(d[j >> 2], j & 3);
}

__global__ __launch_bounds__(256, 4) void stage2_kernel(
    const unsigned char* __restrict__ border, const float* __restrict__ Wg,
    unsigned char* __restrict__ gsp)
{
    __shared__ unsigned tile[R2 * SROW];   // u8 tile, 38.4 KB

    const int z   = blockIdx.z;
    const int b   = z >> 4;
    const int c   = z & 15;
    const int tx0 = blockIdx.x * T2X;
    const unsigned char* bp = border + ((size_t)b * 16 + c) * (HH * WW);

    // ---- stage u8 rows [-11, 523), cols [tx0-12, tx0+52) as dwords ----
    for (int i = threadIdx.x; i < R2 * 16; i += 256) {
        int iy = i >> 4, cc = i & 15;
        int gy  = iy - PAD2;
        int gx0 = tx0 - 12 + 4 * cc;       // 4-aligned; in range iff 0<=gx0<=508
        unsigned u = 0;
        if (((unsigned)gy < HH) & ((unsigned)gx0 < WW))
            u = *(const unsigned*)(bp + (size_t)gy * WW + gx0);
        tile[iy * SROW + cc] = u;
    }
    __syncthreads();

    const int lx = threadIdx.x & 3;    // 4 x-groups of 8 px -> 32 wide
    const int ly = threadIdx.x >> 2;   // 64 y-groups of 8 rows -> 512 tall
    const int px = lx * 8;
    const int py = ly * 8;

    float acc[8][8];
    #pragma unroll
    for (int dy = 0; dy < 8; dy++)
        #pragma unroll
        for (int p = 0; p < 8; p++) acc[dy][p] = 0.f;

    const float* wc = Wg + c * (K2 * K2);

    unsigned dc[8];
    s2_load(tile, py + 0, lx, dc);         // prologue: row t=0

    // ---- boundary rows t=0..6: dy FULLY unrolled, static acc, uniform guard ----
    #pragma unroll 1
    for (int t = 0; t < 7; t++) {
        float a[31];
        s2_cvt(dc, a);                     // previous row's data: no lgkm wait
        s2_load(tile, py + t + 1, lx, dc); // prefetch next; wait lands post-FMA
        #pragma unroll
        for (int dy = 0; dy < 8; dy++) {
            if (t - dy >= 0) {                 // runtime-uniform; acc idx static
                const float* wr = wc + (t - dy) * K2;
                #pragma unroll
                for (int kx = 0; kx < K2; kx++) {
                    const float wv = wr[kx];
                    #pragma unroll
                    for (int p = 0; p < 8; p++)
                        acc[dy][p] = fmaf(a[p + kx + 1], wv, acc[dy][p]);
                }
            }
        }
    }

    // ---- interior rows t=7..22: all 8 dy active, dy innermost, branch-free ----
    #pragma unroll 1
    for (int t = 7; t < 23; t++) {
        float a[31];
        s2_cvt(dc, a);
        s2_load(tile, py + t + 1, lx, dc);
        const float* w0 = wc + t * K2;       // dy=d row is w0[kx - 23*d]
        #pragma unroll
        for (int kx = 0; kx < K2; kx++) {
            float wv[8];
            #pragma unroll
            for (int d = 0; d < 8; d++) wv[d] = w0[kx - 23 * d];
            #pragma unroll
            for (int p = 0; p < 8; p++) {
                const float av = a[p + kx + 1];
                #pragma unroll
                for (int d = 0; d < 8; d++)
                    acc[d][p] = fmaf(av, wv[d], acc[d][p]);
            }
        }
    }

    // ---- boundary rows t=23..28 (prefetching), then peeled t=29 ----
    #pragma unroll 1
    for (int t = 23; t < 29; t++) {
        float a[31];
        s2_cvt(dc, a);
        s2_load(tile, py + t + 1, lx, dc); // py+29 <= 533 < R2: in bounds
        #pragma unroll
        for (int dy = 0; dy < 8; dy++) {
            if (t - dy < K2) {                 // runtime-uniform; acc idx static
                const float* wr = wc + (t - dy) * K2;
                #pragma unroll
                for (int kx = 0; kx < K2; kx++) {
                    const float wv = wr[kx];
                    #pragma unroll
                    for (int p = 0; p < 8; p++)
                        acc[dy][p] = fmaf(a[p + kx + 1], wv, acc[dy][p]);
                }
            }
        }
    }
    {   // t = 29: only dy=7 active (29-dy < 23 -> dy >= 7); no prefetch
        float a[31];
        s2_cvt(dc, a);
        const float* wr = wc + 22 * K2;
        #pragma unroll
        for (int kx = 0; kx < K2; kx++) {
            const float wv = wr[kx];
            #pragma unroll
            for (int p = 0; p < 8; p++)
                acc[7][p] = fmaf(a[p + kx + 1], wv, acc[7][p]);
        }
    }

    // ---- spike + write u8 plane ----
    const int ox = tx0 + px;               // multiple of 8 -> uint2 store OK
    unsigned char* gp = gsp + ((size_t)b * 16 + c) * (HH * WW);
    #pragma unroll
    for (int dy = 0; dy < 8; dy++) {
        const int oy = py + dy;
        unsigned lo = 0, hi = 0;
        #pragma unroll
        for (int p = 0; p < 4; p++) lo |= (acc[dy][p]     >= 1.f ? 1u : 0u) << (8 * p);
        #pragma unroll
        for (int p = 0; p < 4; p++) hi |= (acc[dy][p + 4] >= 1.f ? 1u : 0u) << (8 * p);
        uint2 v; v.x = lo; v.y = hi;
        *(uint2*)&gp[(size_t)oy * WW + ox] = v;
    }
}

// ---------------- Stage 3: combine 16 spike planes -> output ----------------
__global__ __launch_bounds__(256) void combine_kernel(
    const unsigned char* __restrict__ gsp, float* __restrict__ out)
{
    const int idx = blockIdx.x * 256 + threadIdx.x;   // uint granules
    const int b = idx >> 16;
    const int r = idx & 65535;
    const unsigned* g = (const unsigned*)gsp;
    const int pb = b * 16;
    unsigned s = 0;
    #pragma unroll
    for (int o = 0; o < 4; o++) {
        unsigned g0 = g[(size_t)(pb + 4 * o + 0) * 65536 + r];
        unsigned g1 = g[(size_t)(pb + 4 * o + 1) * 65536 + r];
        unsigned g2 = g[(size_t)(pb + 4 * o + 2) * 65536 + r];
        unsigned g3 = g[(size_t)(pb + 4 * o + 3) * 65536 + r];
        s += ((g0 & ~g1) & 0x01010101u) + ((g2 & ~g3) & 0x01010101u);
    }
    float4 f;
    f.x = (float)(s & 255u);
    f.y = (float)((s >> 8) & 255u);
    f.z = (float)((s >> 16) & 255u);
    f.w = (float)(s >> 24);
    ((float4*)out)[idx] = f;
}

extern "C" void kernel_launch(void* const* d_in, const int* in_sizes, int n_in,
                              void* d_out, int out_size, void* d_ws, size_t ws_size,
                              hipStream_t stream)
{
    const float* inp = (const float*)d_in[0];   // (4,2,512,512) f32
    const float* Wb  = (const float*)d_in[1];   // (8,1,11,11)   f32
    const float* Wg  = (const float*)d_in[2];   // (16,1,23,23)  f32
    unsigned char* border = (unsigned char*)d_ws;                       // 16.78 MB
    unsigned char* gsp    = border + (size_t)NB * 16 * HH * WW;         // +16.78 MB
    float* out = (float*)d_out;                 // (4,512,512)   f32

    dim3 blk(256);
    dim3 g1(WW / T1X, HH / T1Y, NB);        // 16x32x4 = 2048 blocks
    stage1_kernel<<<g1, blk, 0, stream>>>(inp, Wb, border);
    dim3 g2(WW / T2X, 1, NB * 16);          // 16x1x64 = 1024 blocks, 4/CU resident
    stage2_kernel<<<g2, blk, 0, stream>>>(border, Wg, gsp);
    dim3 g3((NB * HH * WW / 4) / 256);      // 1024 blocks
    combine_kernel<<<g3, blk, 0, stream>>>(gsp, out);
}

// Round 9
// 263.453 us; speedup vs baseline: 1.8335x; 1.0324x over previous
//
#include <hip/hip_runtime.h>

#define HH 512
#define WW 512
#define NB 4

// ---------------- Stage 1: 11x11 convs (1->8, pos & neg) + spike/WTA logic ----------------
// Round-19: fused pos+neg convs, 4 px/thread (32x32 tile, 1024 blocks).
// Each weight s_load now feeds 8 FMAs (was 4); window ds_reads amortize over
// 4 px (was 2); waves 8192 -> 4096. Same math, same WTA epilogue.
#define K1 11
#define PAD1 5
#define T1X 32
#define T1Y 32
#define IN1 42        // 32 + 10 halo
#define S1B 44        // LDS row stride (even -> b64-aligned float2 reads)

__global__ __launch_bounds__(256, 4) void stage1_kernel(
    const float* __restrict__ inp, const float* __restrict__ Wb,
    unsigned char* __restrict__ border)
{
    __shared__ __align__(16) float s0[IN1 * S1B];
    __shared__ __align__(16) float s1[IN1 * S1B];

    const int b   = blockIdx.z;
    const int tx0 = blockIdx.x * T1X;
    const int ty0 = blockIdx.y * T1Y;
    const float* in0 = inp + ((size_t)b * 2 + 0) * (HH * WW);
    const float* in1 = inp + ((size_t)b * 2 + 1) * (HH * WW);

    for (int i = threadIdx.x; i < IN1 * IN1; i += 256) {
        int iy = i / IN1, ix = i - iy * IN1;
        int gy = ty0 + iy - PAD1, gx = tx0 + ix - PAD1;
        bool ok = (gy >= 0) & (gy < HH) & (gx >= 0) & (gx < WW);
        int idx = gy * WW + gx;
        s0[iy * S1B + ix] = ok ? in0[idx] : 0.f;
        s1[iy * S1B + ix] = ok ? in1[idx] : 0.f;
    }
    __syncthreads();

    const int lx  = threadIdx.x & 7;    // 8 x-groups of 4 px -> 32 wide
    const int ly  = threadIdx.x >> 3;   // 32 rows
    const int px0 = lx * 4;
    const int py  = ly;

    float accP[8][4], accN[8][4];
    #pragma unroll
    for (int c = 0; c < 8; c++)
        #pragma unroll
        for (int p = 0; p < 4; p++) { accP[c][p] = 0.f; accN[c][p] = 0.f; }

    #pragma unroll 1
    for (int ky = 0; ky < K1; ky++) {
        float a0[14], a1[14];
        const float2* r0 = (const float2*)&s0[(py + ky) * S1B + px0];
        const float2* r1 = (const float2*)&s1[(py + ky) * S1B + px0];
        #pragma unroll
        for (int r = 0; r < 7; r++) {
            *(float2*)&a0[2 * r] = r0[r];
            *(float2*)&a1[2 * r] = r1[r];
        }
        #pragma unroll
        for (int c = 0; c < 8; c++) {
            #pragma unroll
            for (int kx = 0; kx < K1; kx++) {
                const float wv = Wb[c * 121 + ky * 11 + kx];  // uniform -> s_load
                #pragma unroll
                for (int p = 0; p < 4; p++) {
                    accP[c][p] = fmaf(a0[kx + p], wv, accP[c][p]);
                    accN[c][p] = fmaf(a1[kx + p], wv, accN[c][p]);
                }
            }
        }
    }

    const int gy  = ty0 + py;
    const int gxb = tx0 + px0;

    float vm[4];
    #pragma unroll
    for (int p = 0; p < 4; p++)
        vm[p] = s0[(py + PAD1) * S1B + px0 + PAD1 + p]
              + s1[(py + PAD1) * S1B + px0 + PAD1 + p];

    float b13[4][4], b24[4][4];
    #pragma unroll
    for (int o = 0; o < 4; o++) {
        #pragma unroll
        for (int p = 0; p < 4; p++) {
            float pe = (accP[2 * o    ][p] >= 1.f) ? 1.f : 0.f;
            float po = (accP[2 * o + 1][p] >= 1.f) ? 1.f : 0.f;
            float ne = (accN[2 * o    ][p] >= 1.f) ? 1.f : 0.f;
            float no = (accN[2 * o + 1][p] >= 1.f) ? 1.f : 0.f;
            float sa = (vm[p] * (pe - 1.5f * no) >= 1.f) ? 1.f : 0.f;
            float sb = (vm[p] * (ne - 1.5f * po) >= 1.f) ? 1.f : 0.f;
            b13[o][p] = sa + sb;
            float sc = (vm[p] * (po - 1.5f * ne) >= 1.f) ? 1.f : 0.f;
            float sd = (vm[p] * (no - 1.5f * pe) >= 1.f) ? 1.f : 0.f;
            b24[o][p] = sc + sd;
        }
    }
    float mxp[4];
    #pragma unroll
    for (int p = 0; p < 4; p++) {
        float m = 0.f;
        #pragma unroll
        for (int o = 0; o < 4; o++) m = fmaxf(m, fabsf(b13[o][p] - b24[o][p]));
        mxp[p] = m;
    }
    #pragma unroll
    for (int o = 0; o < 4; o++) {
        unsigned w0 = 0, w1 = 0, w2 = 0, w3 = 0;
        #pragma unroll
        for (int p = 0; p < 4; p++) {
            float d   = b13[o][p] - b24[o][p];
            float wta = (fabsf(d) == mxp[p]) ? 1.f : 0.f;
            float b1p = (wta * d >= 1.f)    ? 1.f : 0.f;
            float b1n = (-(wta * d) >= 1.f) ? 1.f : 0.f;
            w0 |= (unsigned)(unsigned char)(b1p * b13[o][p]) << (8 * p);
            w1 |= (unsigned)(unsigned char)(b1p * b24[o][p]) << (8 * p);
            w2 |= (unsigned)(unsigned char)(b1n * b24[o][p]) << (8 * p);
            w3 |= (unsigned)(unsigned char)(b1n * b13[o][p]) << (8 * p);
        }
        size_t base = (((size_t)b * 16 + 4 * o) * HH + gy) * WW + gxb;   // gxb % 4 == 0
        *(unsigned*)&border[base]                       = w0;
        *(unsigned*)&border[base + (size_t)HH * WW]     = w1;
        *(unsigned*)&border[base + (size_t)2 * HH * WW] = w2;
        *(unsigned*)&border[base + (size_t)3 * HH * WW] = w3;
    }
}

// ---------------- Stage 2: depthwise 23x23 conv, u8 LDS tile ----------------
// Round-18 version (165.3 us, plateau): 8 output rows/thread, rolling dc[8]
// register prefetch, dy-innermost weight sharing, static acc indices.
#define K2 23
#define PAD2 11
#define T2X 32
#define T2Y 512
#define SROW 18        // LDS row stride in dwords (72 B); even -> b64-aligned reads
#define R2 534         // staged rows: -11 .. 522

__device__ __forceinline__ float ubyte_f(unsigned dw, int byi) {
    return (float)((dw >> (8 * byi)) & 0xffu);   // -> v_cvt_f32_ubyteN
}

// issue one staged row's 4x ds_read_b64 (8 dwords, 30 px window at lx)
__device__ __forceinline__ void s2_load(const unsigned* __restrict__ tile,
                                        int trow, int lx, unsigned d[8])
{
    const uint2* tp2 = (const uint2*)&tile[trow * SROW + 2 * lx];
    #pragma unroll
    for (int r2 = 0; r2 < 4; r2++) {
        uint2 v = tp2[r2];
        d[2 * r2] = v.x; d[2 * r2 + 1] = v.y;
    }
}

__device__ __forceinline__ void s2_cvt(const unsigned d[8], float a[31])
{
    #pragma unroll
    for (int j = 1; j <= 30; j++) a[j] = ubyte_f(d[j >> 2], j & 3);
}

__global__ __launch_bounds__(256, 4) void stage2_kernel(
    const unsigned char* __restrict__ border, const float* __restrict__ Wg,
    unsigned char* __restrict__ gsp)
{
    __shared__ unsigned tile[R2 * SROW];   // u8 tile, 38.4 KB

    const int z   = blockIdx.z;
    const int b   = z >> 4;
    const int c   = z & 15;
    const int tx0 = blockIdx.x * T2X;
    const unsigned char* bp = border + ((size_t)b * 16 + c) * (HH * WW);

    // ---- stage u8 rows [-11, 523), cols [tx0-12, tx0+52) as dwords ----
    for (int i = threadIdx.x; i < R2 * 16; i += 256) {
        int iy = i >> 4, cc = i & 15;
        int gy  = iy - PAD2;
        int gx0 = tx0 - 12 + 4 * cc;       // 4-aligned; in range iff 0<=gx0<=508
        unsigned u = 0;
        if (((unsigned)gy < HH) & ((unsigned)gx0 < WW))
            u = *(const unsigned*)(bp + (size_t)gy * WW + gx0);
        tile[iy * SROW + cc] = u;
    }
    __syncthreads();

    const int lx = threadIdx.x & 3;    // 4 x-groups of 8 px -> 32 wide
    const int ly = threadIdx.x >> 2;   // 64 y-groups of 8 rows -> 512 tall
    const int px = lx * 8;
    const int py = ly * 8;

    float acc[8][8];
    #pragma unroll
    for (int dy = 0; dy < 8; dy++)
        #pragma unroll
        for (int p = 0; p < 8; p++) acc[dy][p] = 0.f;

    const float* wc = Wg + c * (K2 * K2);

    unsigned dc[8];
    s2_load(tile, py + 0, lx, dc);         // prologue: row t=0

    // ---- boundary rows t=0..6: dy FULLY unrolled, static acc, uniform guard ----
    #pragma unroll 1
    for (int t = 0; t < 7; t++) {
        float a[31];
        s2_cvt(dc, a);                     // previous row's data: no lgkm wait
        s2_load(tile, py + t + 1, lx, dc); // prefetch next; wait lands post-FMA
        #pragma unroll
        for (int dy = 0; dy < 8; dy++) {
            if (t - dy >= 0) {                 // runtime-uniform; acc idx static
                const float* wr = wc + (t - dy) * K2;
                #pragma unroll
                for (int kx = 0; kx < K2; kx++) {
                    const float wv = wr[kx];
                    #pragma unroll
                    for (int p = 0; p < 8; p++)
                        acc[dy][p] = fmaf(a[p + kx + 1], wv, acc[dy][p]);
                }
            }
        }
    }

    // ---- interior rows t=7..22: all 8 dy active, dy innermost, branch-free ----
    #pragma unroll 1
    for (int t = 7; t < 23; t++) {
        float a[31];
        s2_cvt(dc, a);
        s2_load(tile, py + t + 1, lx, dc);
        const float* w0 = wc + t * K2;       // dy=d row is w0[kx - 23*d]
        #pragma unroll
        for (int kx = 0; kx < K2; kx++) {
            float wv[8];
            #pragma unroll
            for (int d = 0; d < 8; d++) wv[d] = w0[kx - 23 * d];
            #pragma unroll
            for (int p = 0; p < 8; p++) {
                const float av = a[p + kx + 1];
                #pragma unroll
                for (int d = 0; d < 8; d++)
                    acc[d][p] = fmaf(av, wv[d], acc[d][p]);
            }
        }
    }

    // ---- boundary rows t=23..28 (prefetching), then peeled t=29 ----
    #pragma unroll 1
    for (int t = 23; t < 29; t++) {
        float a[31];
        s2_cvt(dc, a);
        s2_load(tile, py + t + 1, lx, dc); // py+29 <= 533 < R2: in bounds
        #pragma unroll
        for (int dy = 0; dy < 8; dy++) {
            if (t - dy < K2) {                 // runtime-uniform; acc idx static
                const float* wr = wc + (t - dy) * K2;
                #pragma unroll
                for (int kx = 0; kx < K2; kx++) {
                    const float wv = wr[kx];
                    #pragma unroll
                    for (int p = 0; p < 8; p++)
                        acc[dy][p] = fmaf(a[p + kx + 1], wv, acc[dy][p]);
                }
            }
        }
    }
    {   // t = 29: only dy=7 active (29-dy < 23 -> dy >= 7); no prefetch
        float a[31];
        s2_cvt(dc, a);
        const float* wr = wc + 22 * K2;
        #pragma unroll
        for (int kx = 0; kx < K2; kx++) {
            const float wv = wr[kx];
            #pragma unroll
            for (int p = 0; p < 8; p++)
                acc[7][p] = fmaf(a[p + kx + 1], wv, acc[7][p]);
        }
    }

    // ---- spike + write u8 plane ----
    const int ox = tx0 + px;               // multiple of 8 -> uint2 store OK
    unsigned char* gp = gsp + ((size_t)b * 16 + c) * (HH * WW);
    #pragma unroll
    for (int dy = 0; dy < 8; dy++) {
        const int oy = py + dy;
        unsigned lo = 0, hi = 0;
        #pragma unroll
        for (int p = 0; p < 4; p++) lo |= (acc[dy][p]     >= 1.f ? 1u : 0u) << (8 * p);
        #pragma unroll
        for (int p = 0; p < 4; p++) hi |= (acc[dy][p + 4] >= 1.f ? 1u : 0u) << (8 * p);
        uint2 v; v.x = lo; v.y = hi;
        *(uint2*)&gp[(size_t)oy * WW + ox] = v;
    }
}

// ---------------- Stage 3: combine 16 spike planes -> output ----------------
__global__ __launch_bounds__(256) void combine_kernel(
    const unsigned char* __restrict__ gsp, float* __restrict__ out)
{
    const int idx = blockIdx.x * 256 + threadIdx.x;   // uint granules
    const int b = idx >> 16;
    const int r = idx & 65535;
    const unsigned* g = (const unsigned*)gsp;
    const int pb = b * 16;
    unsigned s = 0;
    #pragma unroll
    for (int o = 0; o < 4; o++) {
        unsigned g0 = g[(size_t)(pb + 4 * o + 0) * 65536 + r];
        unsigned g1 = g[(size_t)(pb + 4 * o + 1) * 65536 + r];
        unsigned g2 = g[(size_t)(pb + 4 * o + 2) * 65536 + r];
        unsigned g3 = g[(size_t)(pb + 4 * o + 3) * 65536 + r];
        s += ((g0 & ~g1) & 0x01010101u) + ((g2 & ~g3) & 0x01010101u);
    }
    float4 f;
    f.x = (float)(s & 255u);
    f.y = (float)((s >> 8) & 255u);
    f.z = (float)((s >> 16) & 255u);
    f.w = (float)(s >> 24);
    ((float4*)out)[idx] = f;
}

extern "C" void kernel_launch(void* const* d_in, const int* in_sizes, int n_in,
                              void* d_out, int out_size, void* d_ws, size_t ws_size,
                              hipStream_t stream)
{
    const float* inp = (const float*)d_in[0];   // (4,2,512,512) f32
    const float* Wb  = (const float*)d_in[1];   // (8,1,11,11)   f32
    const float* Wg  = (const float*)d_in[2];   // (16,1,23,23)  f32
    unsigned char* border = (unsigned char*)d_ws;                       // 16.78 MB
    unsigned char* gsp    = border + (size_t)NB * 16 * HH * WW;         // +16.78 MB
    float* out = (float*)d_out;                 // (4,512,512)   f32

    dim3 blk(256);
    dim3 g1(WW / T1X, HH / T1Y, NB);        // 16x16x4 = 1024 blocks
    stage1_kernel<<<g1, blk, 0, stream>>>(inp, Wb, border);
    dim3 g2(WW / T2X, 1, NB * 16);          // 16x1x64 = 1024 blocks, 4/CU resident
    stage2_kernel<<<g2, blk, 0, stream>>>(border, Wg, gsp);
    dim3 g3((NB * HH * WW / 4) / 256);      // 1024 blocks
    combine_kernel<<<g3, blk, 0, stream>>>(gsp, out);
}